// Round 1
// baseline (85.853 us; speedup 1.0000x reference)
//
#include <hip/hip_runtime.h>

// Multivariate Hawkes process log-likelihood, N=8192 events, D=10 types.
// Dominant cost: 33.5M pairwise exp evaluations (strict lower triangle).
//
// ws layout (floats):
//   [0, 8192)        acc[i]   : pairwise interaction sums (atomicAdd targets)
//   [8192, 8202)     mu_s     : softplus(mu)
//   [8208, 8308)     alpha    : softplus(log_alpha), row-major [D][D]
//   [8320, 8420)     beta     : softplus(log_beta)
//   [8432, 8532)     nbl2     : -beta * log2(e)   (exp(-b*dt) = exp2(nbl2*dt))
//   [8544, 8644)     ab       : alpha * beta

#define N_EV 8192
#define DT 10

static constexpr int OFF_ACC   = 0;
static constexpr int OFF_MU    = 8192;
static constexpr int OFF_ALPHA = 8208;
static constexpr int OFF_BETA  = 8320;
static constexpr int OFF_NBL2  = 8432;
static constexpr int OFF_AB    = 8544;

__device__ __forceinline__ float fast_exp2(float x) {
#if __has_builtin(__builtin_amdgcn_exp2f)
    return __builtin_amdgcn_exp2f(x);
#else
    return exp2f(x);
#endif
}

// jax.nn.softplus(x) = max(x,0) + log1p(exp(-|x|))
__device__ __forceinline__ float softplus(float x) {
    return fmaxf(x, 0.0f) + log1pf(expf(-fabsf(x)));
}

// T arrives as a 1-element array of unknown encoding (python int scalar).
// If the float32 interpretation is plausible use it, else the int32 one.
__device__ __forceinline__ float read_T(const void* p) {
    float f = *(const float*)p;
    if (f > 0.5f && f < 1.0e9f) return f;
    return (float)(*(const int*)p);
}

__global__ void hawkes_prep(const float* __restrict__ mu,
                            const float* __restrict__ la,
                            const float* __restrict__ lb,
                            float* __restrict__ ws) {
    int t = threadIdx.x;
    if (t < DT * DT) {
        float a = softplus(la[t]);
        float b = softplus(lb[t]);
        ws[OFF_ALPHA + t] = a;
        ws[OFF_BETA  + t] = b;
        ws[OFF_NBL2  + t] = -b * 1.4426950408889634f;
        ws[OFF_AB    + t] = a * b;
    }
    if (t < DT) ws[OFF_MU + t] = softplus(mu[t]);
}

// Phase A: pairwise sums. Block (jb, ib) handles i in [ib*256, ib*256+256),
// j in [jb*256, jb*256+256), strictly lower triangular (j < i).
__global__ __launch_bounds__(256) void hawkes_pairs(
        const float* __restrict__ tp, const int* __restrict__ et,
        const float* __restrict__ ws, float* __restrict__ acc) {
    const int ib = blockIdx.y, jb = blockIdx.x;
    if (jb > ib) return;

    __shared__ float2 te_s[256];          // (t_j, e_j-as-float-bits)
    __shared__ float2 tab_s[DT * DT];     // (nbl2, ab)

    const int tid = threadIdx.x;
    if (tid < DT * DT)
        tab_s[tid] = make_float2(ws[OFF_NBL2 + tid], ws[OFF_AB + tid]);
    const int j0 = jb << 8;
    te_s[tid] = make_float2(tp[j0 + tid], __int_as_float(et[j0 + tid]));
    __syncthreads();

    const int i = (ib << 8) + tid;
    const float ti = tp[i];
    const int rowb = et[i] * DT;
    const int cnt = (ib == jb) ? tid : 256;   // strict j < i on the diagonal

    float a0 = 0.0f, a1 = 0.0f;
    int j = 0;
#pragma unroll 2
    for (; j + 2 <= cnt; j += 2) {
        float2 te0 = te_s[j];
        float2 te1 = te_s[j + 1];
        float2 tb0 = tab_s[rowb + __float_as_int(te0.y)];
        float2 tb1 = tab_s[rowb + __float_as_int(te1.y)];
        a0 = fmaf(tb0.y, fast_exp2(tb0.x * (ti - te0.x)), a0);
        a1 = fmaf(tb1.y, fast_exp2(tb1.x * (ti - te1.x)), a1);
    }
    if (j < cnt) {
        float2 te0 = te_s[j];
        float2 tb0 = tab_s[rowb + __float_as_int(te0.y)];
        a0 = fmaf(tb0.y, fast_exp2(tb0.x * (ti - te0.x)), a0);
    }
    const float tot = a0 + a1;
    if (cnt > 0) atomicAdd(&acc[i], tot);
}

// Phase B: per-event log-intensity minus integral tail, reduce to scalar.
__global__ __launch_bounds__(256) void hawkes_finish(
        const float* __restrict__ tp, const int* __restrict__ et,
        const float* __restrict__ ws, const void* __restrict__ Tp,
        float* __restrict__ out) {
    const int i = blockIdx.x * 256 + threadIdx.x;
    const float Tf = read_T(Tp);
    const float ti = tp[i];
    const int e = et[i];

    const float inten = ws[OFF_MU + e] + ws[OFF_ACC + i];
    const float ll = logf(inten);

    const float delta = Tf - ti;
    float contrib = 0.0f;
#pragma unroll
    for (int d = 0; d < DT; ++d) {
        float a  = ws[OFF_ALPHA + d * DT + e];
        float nb = ws[OFF_NBL2  + d * DT + e];
        contrib += a * (1.0f - fast_exp2(nb * delta));
    }
    float val = ll - contrib;

    if (i == 0) {
        float s = 0.0f;
#pragma unroll
        for (int d = 0; d < DT; ++d) s += ws[OFF_MU + d];
        val -= s * Tf;   // -T * sum(mu_s)
    }

    // wave reduce (64 lanes) then cross-wave via LDS
    for (int o = 32; o > 0; o >>= 1) val += __shfl_down(val, o);
    __shared__ float wsum[4];
    const int lane = threadIdx.x & 63, wv = threadIdx.x >> 6;
    if (lane == 0) wsum[wv] = val;
    __syncthreads();
    if (threadIdx.x == 0)
        atomicAdd(out, wsum[0] + wsum[1] + wsum[2] + wsum[3]);
}

extern "C" void kernel_launch(void* const* d_in, const int* in_sizes, int n_in,
                              void* d_out, int out_size, void* d_ws, size_t ws_size,
                              hipStream_t stream) {
    const float* tp = (const float*)d_in[0];
    const int*   et = (const int*)d_in[1];
    const float* mu = (const float*)d_in[2];
    const float* la = (const float*)d_in[3];
    const float* lb = (const float*)d_in[4];
    const void*  Tp = d_in[5];
    float* out = (float*)d_out;
    float* ws  = (float*)d_ws;

    hipMemsetAsync(ws, 0, N_EV * sizeof(float), stream);
    hipMemsetAsync(out, 0, sizeof(float), stream);

    hawkes_prep<<<1, 128, 0, stream>>>(mu, la, lb, ws);

    dim3 grid(32, 32);
    hawkes_pairs<<<grid, 256, 0, stream>>>(tp, et, ws, ws + OFF_ACC);

    hawkes_finish<<<N_EV / 256, 256, 0, stream>>>(tp, et, ws, Tp, out);
}